// Round 1
// 198.150 us; speedup vs baseline: 1.0059x; 1.0059x over previous
//
#include <hip/hip_runtime.h>

// FullPairwise (non-PBC), M=4 x N=2048 (fixed by reference setup_inputs).
// P = N*(N-1)/2 = 2,096,128; MP = 4*P = 8,384,512.
// d_out: 6*MP float32 elements, outputs concatenated flat:
//   [0,   MP)   atom_index12 row 0   (i + m*N)
//   [MP,  2MP)  atom_index12 row 1   (j + m*N)
//   [2MP, 5MP)  shift_values zeros   ([MP,3] row-major)
//   [5MP, 6MP)  mask                 (1.0 if d2 <= 5.2^2 else 0.0)
//
// Store-pattern lessons (Rounds 8/9): nontemporal stores -> 2.17x HBM write
// amplification, 5x slower. PV=8 per-thread (lane stride 32B) -> ~13us slower
// than PV=4 (lane stride 16B, perfect 1KB wave bursts). Store pattern here is
// IDENTICAL to the 199us version.
//
// Round 10 theory: kernel (~79us of the 199us; the other ~120us is the
// harness re-poison fill at 6.6 TB/s) is TA/L1-bound, not write-bound.
// With PV=4, lane j-stride is 4 atoms = 48B -> each cm[3j+c] wave-load
// gathers ~48 distinct cachelines; 144 line-transactions per pair-quad/wave
// contend with the stores on the vector-memory pipe. Fix: stage the
// molecule's coords (24KB) in LDS once per block; all i/j reads become LDS
// reads. Padded layout addr(j,c) = 3j + c + (j>>3) (1 pad dword per 8 atoms)
// makes the stride-4-j lane pattern ~2-way bank-aliased (free per m136).

#define NA    2048
#define PPM   2096128      // 1024 | PPM -> a 1024-pair chunk never crosses molecules
#define MPTOT 8384512      // MPTOT / 2048 = 4094 blocks exact
#define LDSN  (6144 + 256) // 6144 coord dwords + 1 pad dword per 24

typedef float f4 __attribute__((ext_vector_type(4)));

__global__ __launch_bounds__(256) void FullPairwise_48241072668760_kernel(
        const float* __restrict__ coords, float* __restrict__ out) {
#pragma clang fp contract(off)
    __shared__ float lds[LDSN];
    const int B = blockIdx.x * 2048;       // block covers 2048 pairs
    const int t = threadIdx.x;
    const float cutoff2 = 5.2f * 5.2f;     // RNE constant fold, as numpy

    int m_staged = -1;
    #pragma unroll
    for (int c = 0; c < 2; ++c) {
        const int qb = B + c * 1024;       // chunk base (single molecule)
        const int q0 = qb + 4 * t;         // this thread's 4 pairs

        const int m = (unsigned int)qb / PPM;  // uniform across block (1024|PPM)

        if (m != m_staged) {
            __syncthreads();               // all waves done with previous stage
            const float* cm = coords + m * (NA * 3);
            #pragma unroll
            for (int w = 0; w < 6; ++w) {
                // thread t copies f4 groups at dword 4*(t+256w): coalesced
                // 16B/lane global loads; LDS addr = d + d/24 inserts the pad.
                // Within a 4-dword group (4*d4 mod 24 <= 20) the pad count is
                // constant, so the 4 LDS writes stay contiguous.
                int d4 = t + 256 * w;                  // 0..1535
                f4 v = *(const f4*)(cm + 4 * d4);
                int a = 4 * d4 + d4 / 6;               // = d + d/24
                lds[a]     = v.x;
                lds[a + 1] = v.y;
                lds[a + 2] = v.z;
                lds[a + 3] = v.w;
            }
            __syncthreads();
            m_staged = m;
        }

        int p = q0 - m * PPM;
        const float mbase = (float)(m * NA);

        // closed-form triangular inversion; disc in [9, 4095^2] < 2^24 -> exact
        // f32; fixup loops absorb sqrt rounding.
        float s = sqrtf((float)(4095 * 4095 - 8 * p));
        int i = (int)((4095.0f - s) * 0.5f);
        if (i < 0) i = 0;
        if (i > NA - 2) i = NA - 2;
        while (i > 0 && ((i * (2 * NA - 1 - i)) >> 1) > p) --i;
        int len     = NA - 1 - i;                       // row length of i
        int rs_next = ((i * (2 * NA - 1 - i)) >> 1) + len;   // row_start(i+1)
        while (rs_next <= p) { ++i; --len; rs_next += len; }

        float r0[4], r1[4], mk[4];
        int ia = 3 * i + (i >> 3);
        float cix = lds[ia], ciy = lds[ia + 1], ciz = lds[ia + 2];
        int cur_i = i;

        #pragma unroll
        for (int k = 0; k < 4; ++k) {
            while (rs_next <= p) { ++i; --len; rs_next += len; }  // add/cmp only
            if (i != cur_i) {
                cur_i = i;
                ia = 3 * i + (i >> 3);
                cix = lds[ia]; ciy = lds[ia + 1]; ciz = lds[ia + 2];
            }
            int j = i + 1 + (p - (rs_next - len));  // rs_next - len = row_start(i)

            // contract(off): exact RN f32, numpy's (dx*dx + dy*dy) + dz*dz order
            int ja = 3 * j + (j >> 3);
            float dx = cix - lds[ja];
            float dy = ciy - lds[ja + 1];
            float dz = ciz - lds[ja + 2];
            float d2 = (dx * dx + dy * dy) + dz * dz;

            r0[k] = mbase + (float)i;
            r1[k] = mbase + (float)j;
            mk[k] = (d2 <= cutoff2) ? 1.0f : 0.0f;
            ++p;
        }

        // index + mask streams: lane stride 16B -> perfect 1KB wave bursts
        *(f4*)(out + q0)             = (f4){r0[0], r0[1], r0[2], r0[3]};
        *(f4*)(out + MPTOT + q0)     = (f4){r1[0], r1[1], r1[2], r1[3]};
        *(f4*)(out + 5 * MPTOT + q0) = (f4){mk[0], mk[1], mk[2], mk[3]};

        // shift zeros for this chunk: 3*1024 floats, written as three fully
        // contiguous wave bursts (decoupled from pair indexing — zeros are
        // position-independent).
        float* zb = out + 2 * MPTOT + 3 * qb;
        f4 z = {0.f, 0.f, 0.f, 0.f};
        *(f4*)(zb + 4 * t)        = z;
        *(f4*)(zb + 1024 + 4 * t) = z;
        *(f4*)(zb + 2048 + 4 * t) = z;
    }
}

extern "C" void kernel_launch(void* const* d_in, const int* in_sizes, int n_in,
                              void* d_out, int out_size, void* d_ws, size_t ws_size,
                              hipStream_t stream) {
    // inputs in setup_inputs() order: species [4,2048] int32, coordinates
    // [4,2048,3] float32, cell [3,3] float32, pbc [3] bool
    const float* coords = (const float*)d_in[1];
    float* out = (float*)d_out;

    FullPairwise_48241072668760_kernel<<<MPTOT / 2048, 256, 0, stream>>>(coords, out);
}